// Round 4
// baseline (1016.325 us; speedup 1.0000x reference)
//
#include <hip/hip_runtime.h>

#define TS 512
#define LOG2E 1.4426950408889634f

typedef _Float16 f16x8 __attribute__((ext_vector_type(8)));
typedef float f32x4 __attribute__((ext_vector_type(4)));

#define MFMA16(a, b, c) __builtin_amdgcn_mfma_f32_16x16x32_f16((a), (b), (c), 0, 0, 0)

// ws (f16) layout (weights pre-scaled by log2e):
//  Region A (L1 B-frags): idx = ((w*16 + g*4 + kt)*64 + l)*8 + j, value = W1[n][k]*log2e
//      n = g*128 + w*16 + (l&15), k = kt*32 + (l>>4)*8 + j        (65536 f16)
//  Region B (L2 B-frags): idx = 65536 + ((w*24 + g*6 + kt)*64 + l)*8 + j
//      n = g*64 + (w&3)*16 + (l&15), k = kt*32 + (l>>4)*8 + j, W2cat = [w_ih2 | w_hh2]
__global__ __launch_bounds__(512) void prep(
    const float* __restrict__ w_hh1, const float* __restrict__ w_ih2,
    const float* __restrict__ w_hh2, _Float16* __restrict__ wsh)
{
  int idx = blockIdx.x * 512 + threadIdx.x;   // 163840 total
  int slot = idx >> 3, j = idx & 7;
  float v;
  if (slot < 8192) {
    int w = slot >> 10, f = (slot >> 6) & 15, l = slot & 63;
    int g = f >> 2, kt = f & 3;
    int n = g * 128 + w * 16 + (l & 15);
    int k = kt * 32 + (l >> 4) * 8 + j;
    v = w_hh1[n * 128 + k];
  } else {
    int s2 = slot - 8192;
    int w = s2 / 1536, rem = s2 % 1536, f = rem >> 6, l = rem & 63;
    int g = f / 6, kt = f % 6;
    int n = g * 64 + (w & 3) * 16 + (l & 15);
    int k = kt * 32 + (l >> 4) * 8 + j;
    v = (k < 128) ? w_ih2[n * 128 + k] : w_hh2[n * 64 + (k - 128)];
  }
  wsh[idx] = (_Float16)(v * LOG2E);
}

__device__ __forceinline__ float rcpf_(float x) { return __builtin_amdgcn_rcpf(x); }
// s = (true preact) * log2e  (weights/biases pre-scaled)
__device__ __forceinline__ float sig_s(float s)  { return rcpf_(1.0f + exp2f(-s)); }
__device__ __forceinline__ float tanh_s(float s) { return 1.0f - 2.0f * rcpf_(exp2f(s + s) + 1.0f); }
// c in true units
__device__ __forceinline__ float tanh_c(float c) { return 1.0f - 2.0f * rcpf_(exp2f(c * (2.0f * LOG2E)) + 1.0f); }

// HC plane (fragment-linear): plane = 6 chunks of 1KB; chunk kt (32 k-units),
// element (row r, k): lane = r + ((k>>3)&3)*16, byte = kt*1024 + lane*16 + (k&7)*2.
// k 0..127 = h1 units, k 128..191 = h2 units. Rows 8..15 permanently zero.
__global__ __launch_bounds__(512, 2) void lstm_mfma(
    const float* __restrict__ x,
    const float* __restrict__ w_ih1,
    const float* __restrict__ b_ih1, const float* __restrict__ b_hh1,
    const float* __restrict__ b_ih2, const float* __restrict__ b_hh2,
    const float* __restrict__ w_d1, const float* __restrict__ b_d1,
    const float* __restrict__ w_d2, const float* __restrict__ b_d2,
    const _Float16* __restrict__ wsh,
    float* __restrict__ out)
{
  __shared__ __align__(16) _Float16 HC[2 * 3072];   // 12 KB, two planes
  __shared__ __align__(16) float x_lds[8 * 516];    // 16.5 KB
  __shared__ float h2f[8][65];
  __shared__ float dh[200];

  const int tid = threadIdx.x;
  const int w   = tid >> 6;      // wave 0..7
  const int l   = tid & 63;
  const int col = l & 15;
  const int q   = l >> 4;
  const int r0  = blockIdx.x * 8;

  // ---- persistent B-fragments (weights, *log2e) in registers ----
  f16x8 B1[4][4];
  #pragma unroll
  for (int g = 0; g < 4; ++g)
    #pragma unroll
    for (int kt = 0; kt < 4; ++kt)
      B1[g][kt] = *(const f16x8*)(wsh + ((w * 16 + g * 4 + kt) * 64 + l) * 8);
  f16x8 B2[4][6];
  #pragma unroll
  for (int g = 0; g < 4; ++g)
    #pragma unroll
    for (int kt = 0; kt < 6; ++kt)
      B2[g][kt] = *(const f16x8*)(wsh + 65536 + ((w * 24 + g * 6 + kt) * 64 + l) * 8);

  // ---- per-lane scalar params (scaled by log2e) ----
  const int u  = w * 16 + col;          // L1 unit
  const int u2 = (w & 3) * 16 + col;    // L2 unit
  float bi1[4], wx1[4], bi2[4];
  #pragma unroll
  for (int g = 0; g < 4; ++g) {
    bi1[g] = (b_ih1[g * 128 + u] + b_hh1[g * 128 + u]) * LOG2E;
    wx1[g] = w_ih1[g * 128 + u] * LOG2E;
    bi2[g] = (b_ih2[g * 64 + u2] + b_hh2[g * 64 + u2]) * LOG2E;
  }

  // ---- x -> LDS (stride 516 words), zero both h planes ----
  {
    int r = tid >> 6, c = (tid & 63) * 8;
    const float4* src = (const float4*)(x + (r0 + r) * 512 + c);
    float4 v0 = src[0], v1 = src[1];
    *(float4*)(x_lds + r * 516 + c)     = v0;
    *(float4*)(x_lds + r * 516 + c + 4) = v1;
  }
  for (int i = tid; i < 3072; i += 512) ((unsigned*)HC)[i] = 0u;

  // ---- address precompute ----
  const int lofs = l * 16;   // A-frag slot (bytes) within a kt-chunk
  const int regbase = (w < 4) ? 0 : 2;
  const int wh1base = (u >> 5) * 1024 + (((u >> 3) & 3) * 16 + 4 * q) * 16 + (u & 7) * 2;
  const int wh2base = (4 + (u2 >> 5)) * 1024
                    + ((4 * q + regbase) + ((u2 >> 3) & 3) * 16) * 16 + (u2 & 7) * 2;

  float c1[4] = {0.f, 0.f, 0.f, 0.f};
  float c2[2] = {0.f, 0.f};
  char* const hcb = (char*)HC;

  __syncthreads();

  #pragma unroll 2
  for (int t = 0; t < TS; ++t) {
    char* pW = hcb + ((t & 1) ? 6144 : 0);   // h1[t] / h2[t]
    char* pR = hcb + ((t & 1) ? 0 : 6144);   // h1[t-1] / h2[t-1]

    // ================= Phase A: layer 1 =================
    f16x8 a0 = *(const f16x8*)(pR + lofs);
    f16x8 a1 = *(const f16x8*)(pR + lofs + 1024);
    f16x8 a2 = *(const f16x8*)(pR + lofs + 2048);
    f16x8 a3 = *(const f16x8*)(pR + lofs + 3072);
    f32x4 accL1[4];
    #pragma unroll
    for (int g = 0; g < 4; ++g) {
      accL1[g] = (f32x4){0.f, 0.f, 0.f, 0.f};
      accL1[g] = MFMA16(a0, B1[g][0], accL1[g]);
      accL1[g] = MFMA16(a1, B1[g][1], accL1[g]);
      accL1[g] = MFMA16(a2, B1[g][2], accL1[g]);
      accL1[g] = MFMA16(a3, B1[g][3], accL1[g]);
    }
    #pragma unroll
    for (int reg = 0; reg < 4; ++reg) {
      const int rr = (q < 2) ? (4 * q + reg) : reg;     // clamp for dead lanes
      const float xv = x_lds[rr * 516 + t];
      float s0 = fmaf(xv, wx1[0], accL1[0][reg] + bi1[0]);
      float s1 = fmaf(xv, wx1[1], accL1[1][reg] + bi1[1]);
      float s2 = fmaf(xv, wx1[2], accL1[2][reg] + bi1[2]);
      float s3 = fmaf(xv, wx1[3], accL1[3][reg] + bi1[3]);
      float ii = sig_s(s0), ff = sig_s(s1), gg = tanh_s(s2), oo = sig_s(s3);
      c1[reg] = fmaf(ff, c1[reg], ii * gg);
      float hv = oo * tanh_c(c1[reg]);
      if (q < 2)
        *(_Float16*)(pW + (wh1base + reg * 16)) = (_Float16)hv;
    }
    __syncthreads();   // the only barrier per step

    // ================= Phase B: layer 2 (K = [h1(t) | h2(t-1)]) =================
    f16x8 e0 = *(const f16x8*)(pW + lofs);
    f16x8 e1 = *(const f16x8*)(pW + lofs + 1024);
    f16x8 e2 = *(const f16x8*)(pW + lofs + 2048);
    f16x8 e3 = *(const f16x8*)(pW + lofs + 3072);
    f16x8 e4 = *(const f16x8*)(pR + lofs + 4096);
    f16x8 e5 = *(const f16x8*)(pR + lofs + 5120);
    f32x4 accL2[4];
    #pragma unroll
    for (int g = 0; g < 4; ++g) {
      accL2[g] = (f32x4){0.f, 0.f, 0.f, 0.f};
      accL2[g] = MFMA16(e0, B2[g][0], accL2[g]);
      accL2[g] = MFMA16(e1, B2[g][1], accL2[g]);
      accL2[g] = MFMA16(e2, B2[g][2], accL2[g]);
      accL2[g] = MFMA16(e3, B2[g][3], accL2[g]);
      accL2[g] = MFMA16(e4, B2[g][4], accL2[g]);
      accL2[g] = MFMA16(e5, B2[g][5], accL2[g]);
    }
    #pragma unroll
    for (int s = 0; s < 2; ++s) {
      float g0 = (w < 4) ? accL2[0][s] : accL2[0][2 + s];
      float g1 = (w < 4) ? accL2[1][s] : accL2[1][2 + s];
      float g2 = (w < 4) ? accL2[2][s] : accL2[2][2 + s];
      float g3 = (w < 4) ? accL2[3][s] : accL2[3][2 + s];
      float ii = sig_s(g0 + bi2[0]), ff = sig_s(g1 + bi2[1]);
      float gg = tanh_s(g2 + bi2[2]), oo = sig_s(g3 + bi2[3]);
      c2[s] = fmaf(ff, c2[s], ii * gg);
      float h2v = oo * tanh_c(c2[s]);
      if (q < 2) {
        *(_Float16*)(pW + (wh2base + s * 16)) = (_Float16)h2v;
        if (t == TS - 1) h2f[4 * q + regbase + s][u2] = h2v;
      }
    }
  }

  // ---- dense head (fp32) ----
  __syncthreads();
  if (tid < 200) {
    int r = tid / 25, d = tid - r * 25;
    float acc = b_d1[d];
    #pragma unroll
    for (int uu = 0; uu < 64; ++uu) acc = fmaf(h2f[r][uu], w_d1[d * 64 + uu], acc);
    dh[tid] = acc;
  }
  __syncthreads();
  if (tid < 8) {
    float y = b_d2[0];
    #pragma unroll
    for (int d = 0; d < 25; ++d) y = fmaf(dh[tid * 25 + d], w_d2[d], y);
    out[r0 + tid] = y;
  }
}

extern "C" void kernel_launch(void* const* d_in, const int* in_sizes, int n_in,
                              void* d_out, int out_size, void* d_ws, size_t ws_size,
                              hipStream_t stream) {
  (void)in_sizes; (void)n_in; (void)out_size; (void)ws_size;
  const float* x     = (const float*)d_in[0];
  const float* w_ih1 = (const float*)d_in[1];
  const float* w_hh1 = (const float*)d_in[2];
  const float* b_ih1 = (const float*)d_in[3];
  const float* b_hh1 = (const float*)d_in[4];
  const float* w_ih2 = (const float*)d_in[5];
  const float* w_hh2 = (const float*)d_in[6];
  const float* b_ih2 = (const float*)d_in[7];
  const float* b_hh2 = (const float*)d_in[8];
  const float* w_d1  = (const float*)d_in[9];
  const float* b_d1  = (const float*)d_in[10];
  const float* w_d2  = (const float*)d_in[11];
  const float* b_d2  = (const float*)d_in[12];
  _Float16* wsh = (_Float16*)d_ws;
  float* outp = (float*)d_out;

  prep<<<320, 512, 0, stream>>>(w_hh1, w_ih2, w_hh2, wsh);
  lstm_mfma<<<256, 512, 0, stream>>>(x, w_ih1, b_ih1, b_hh1, b_ih2, b_hh2,
                                     w_d1, b_d1, w_d2, b_d2, wsh, outp);
}

// Round 5
// 564.424 us; speedup vs baseline: 1.8006x; 1.8006x over previous
//
#include <hip/hip_runtime.h>

#define TS 512
#define LOG2E 1.4426950408889634f

typedef _Float16 f16x8 __attribute__((ext_vector_type(8)));
typedef float f32x4 __attribute__((ext_vector_type(4)));

#define MFMA16(a, b, c) __builtin_amdgcn_mfma_f32_16x16x32_f16((a), (b), (c), 0, 0, 0)

// ws (f16), all values pre-scaled by log2e:
//  L1 region [0, 65536): idx = ((w*32 + tau*4 + kt)*64 + l)*8 + j
//      = w_hh1[n*128 + k], n = (tau>>1)*128 + w*32 + (tau&1)*16 + (l&15),
//        k = kt*32 + (l>>4)*8 + j                      (w = 0..3)
//  L2 region [65536, 114688): idx = 65536 + ((w2*24 + g*6 + kt)*64 + l)*8 + j
//      = W2cat[n][k], n = g*64 + w2*16 + (l&15), k = kt*32 + (l>>4)*8 + j
//        W2cat = [w_ih2 (k<128) | w_hh2 (k>=128)]      (w2 = 0..3)
__global__ __launch_bounds__(512) void prep(
    const float* __restrict__ w_hh1, const float* __restrict__ w_ih2,
    const float* __restrict__ w_hh2, _Float16* __restrict__ wsh)
{
  int idx = blockIdx.x * 512 + threadIdx.x;   // 114688 total
  if (idx >= 114688) return;
  int slot = idx >> 3, j = idx & 7;
  float v;
  if (slot < 8192) {
    int l = slot & 63, fi = slot >> 6;        // fi = w*32 + f
    int w = fi >> 5, f = fi & 31, tau = f >> 2, kt = f & 3;
    int n = (tau >> 1) * 128 + w * 32 + (tau & 1) * 16 + (l & 15);
    int k = kt * 32 + (l >> 4) * 8 + j;
    v = w_hh1[n * 128 + k];
  } else {
    int s2 = slot - 8192;
    int l = s2 & 63, fi = s2 >> 6;            // fi = w2*24 + f
    int w2 = fi / 24, f = fi % 24, g = f / 6, kt = f % 6;
    int n = g * 64 + w2 * 16 + (l & 15);
    int k = kt * 32 + (l >> 4) * 8 + j;
    v = (k < 128) ? w_ih2[n * 128 + k] : w_hh2[n * 64 + (k - 128)];
  }
  wsh[idx] = (_Float16)(v * LOG2E);
}

__device__ __forceinline__ float rcpf_(float x) { return __builtin_amdgcn_rcpf(x); }
__device__ __forceinline__ float sig_s(float s)  { return rcpf_(1.0f + exp2f(-s)); }
__device__ __forceinline__ float tanh_s(float s) { return 1.0f - 2.0f * rcpf_(exp2f(s + s) + 1.0f); }
__device__ __forceinline__ float tanh_c(float c) { return 1.0f - 2.0f * rcpf_(exp2f(c * (2.0f * LOG2E)) + 1.0f); }

// HC plane (fragment-linear): plane = 6 chunks of 1KB; chunk kt = k in [kt*32, kt*32+32).
// Element (row r, k): lane = r + ((k>>3)&3)*16, byte = kt*1024 + lane*16 + (k&7)*2.
// k 0..127 = h1, k 128..191 = h2. Rows 8..15 permanently zero.
// Interval i: L1 waves (0-3) compute h1[i]: read chunks0-3 of PL(i-1), write chunks0-3 of PL(i).
//             L2 waves (4-7) compute h2[i-1]: read chunks0-3 of PL(i-1) + chunks4-5 of PL(i),
//                                             write chunks4-5 of PL(i-1).   All disjoint. 1 barrier.

#define L1_BODY(I, PI, PIM)                                                    \
  {                                                                            \
    f16x8 a0 = *(const f16x8*)((PIM) + lofs);                                  \
    f16x8 a1 = *(const f16x8*)((PIM) + lofs + 1024);                           \
    f16x8 a2 = *(const f16x8*)((PIM) + lofs + 2048);                           \
    f16x8 a3 = *(const f16x8*)((PIM) + lofs + 3072);                           \
    f32x4 acc[8];                                                              \
    _Pragma("unroll") for (int tau = 0; tau < 8; ++tau) {                      \
      acc[tau] = (f32x4){biv[tau], biv[tau], biv[tau], biv[tau]};              \
      acc[tau] = MFMA16(a0, BF[tau * 4 + 0], acc[tau]);                        \
      acc[tau] = MFMA16(a1, BF[tau * 4 + 1], acc[tau]);                        \
      acc[tau] = MFMA16(a2, BF[tau * 4 + 2], acc[tau]);                        \
      acc[tau] = MFMA16(a3, BF[tau * 4 + 3], acc[tau]);                        \
    }                                                                          \
    const float xv0 = x_lds[(rb + 0) * 516 + (I)];                             \
    const float xv1 = x_lds[(rb + 1) * 516 + (I)];                             \
    _Pragma("unroll") for (int c = 0; c < 2; ++c) {                            \
      _Pragma("unroll") for (int rr = 0; rr < 2; ++rr) {                       \
        const float xv = rr ? xv1 : xv0;                                       \
        float sv[4];                                                           \
        _Pragma("unroll") for (int g = 0; g < 4; ++g) {                        \
          const int tau = g * 2 + c;                                           \
          const float oth = __shfl_xor(acc[tau][2 + rr], 32, 64);              \
          const float mine = acc[tau][rr];                                     \
          sv[g] = fmaf(xv, wxv[tau], up ? oth : mine);                         \
        }                                                                      \
        const float ii = sig_s(sv[0]), ff = sig_s(sv[1]);                      \
        const float gv = tanh_s(sv[2]), oo = sig_s(sv[3]);                     \
        const int ci = c * 2 + rr;                                             \
        cst[ci] = fmaf(ff, cst[ci], ii * gv);                                  \
        const float hv = oo * tanh_c(cst[ci]);                                 \
        *(_Float16*)((PI) + ha[ci]) = (_Float16)hv;                            \
      }                                                                        \
    }                                                                          \
  }

#define L2_BODY(PI, PIM, WRLDS, WRF)                                           \
  {                                                                            \
    f16x8 e0 = *(const f16x8*)((PIM) + lofs);                                  \
    f16x8 e1 = *(const f16x8*)((PIM) + lofs + 1024);                           \
    f16x8 e2 = *(const f16x8*)((PIM) + lofs + 2048);                           \
    f16x8 e3 = *(const f16x8*)((PIM) + lofs + 3072);                           \
    f16x8 e4 = *(const f16x8*)((PI) + lofs + 4096);                            \
    f16x8 e5 = *(const f16x8*)((PI) + lofs + 5120);                            \
    f32x4 acc[4];                                                              \
    _Pragma("unroll") for (int g = 0; g < 4; ++g) {                            \
      acc[g] = (f32x4){biv[g], biv[g], biv[g], biv[g]};                        \
      acc[g] = MFMA16(e0, BF[g * 6 + 0], acc[g]);                              \
      acc[g] = MFMA16(e1, BF[g * 6 + 1], acc[g]);                              \
      acc[g] = MFMA16(e2, BF[g * 6 + 2], acc[g]);                              \
      acc[g] = MFMA16(e3, BF[g * 6 + 3], acc[g]);                              \
      acc[g] = MFMA16(e4, BF[g * 6 + 4], acc[g]);                              \
      acc[g] = MFMA16(e5, BF[g * 6 + 5], acc[g]);                              \
    }                                                                          \
    _Pragma("unroll") for (int rr = 0; rr < 2; ++rr) {                         \
      float sv[4];                                                             \
      _Pragma("unroll") for (int g = 0; g < 4; ++g) {                          \
        const float oth = __shfl_xor(acc[g][2 + rr], 32, 64);                  \
        const float mine = acc[g][rr];                                         \
        sv[g] = up ? oth : mine;                                               \
      }                                                                        \
      const float ii = sig_s(sv[0]), ff = sig_s(sv[1]);                        \
      const float gv = tanh_s(sv[2]), oo = sig_s(sv[3]);                       \
      cst[rr] = fmaf(ff, cst[rr], ii * gv);                                    \
      const float hv = oo * tanh_c(cst[rr]);                                   \
      if (WRLDS) *(_Float16*)((PIM) + ha[rr]) = (_Float16)hv;                  \
      if (WRF) h2f[rb + rr][w2 * 16 + col] = hv;                               \
    }                                                                          \
  }

__global__ __launch_bounds__(512, 2) void lstm_mfma(
    const float* __restrict__ x,
    const float* __restrict__ w_ih1,
    const float* __restrict__ b_ih1, const float* __restrict__ b_hh1,
    const float* __restrict__ b_ih2, const float* __restrict__ b_hh2,
    const float* __restrict__ w_d1, const float* __restrict__ b_d1,
    const float* __restrict__ w_d2, const float* __restrict__ b_d2,
    const _Float16* __restrict__ wsh,
    float* __restrict__ out)
{
  __shared__ __align__(16) _Float16 HC[2 * 3072];   // 12 KB, two planes
  __shared__ __align__(16) float x_lds[8 * 516];    // 16.5 KB
  __shared__ float h2f[8][65];
  __shared__ float dh[200];

  const int tid = threadIdx.x;
  const int w   = tid >> 6;        // wave 0..7
  const int l   = tid & 63;
  const int col = l & 15;
  const int qh  = (l >> 4) & 1;
  const int up  = l >> 5;          // upper half-wave handles acc rows 2,3
  const int rb  = 4 * qh + 2 * up; // row base: {0,4,2,6} for q=0..3
  const int wg  = w >> 2;          // 0 = layer-1 waves, 1 = layer-2 waves
  const int w2  = w & 3;
  const int r0  = blockIdx.x * 8;
  const int lofs = l * 16;

  f16x8 BF[32];                    // unified weight regs (L1: 32 frags, L2: 24)
  float biv[8], wxv[8];
  int ha[4];

  if (wg == 0) {
    #pragma unroll
    for (int f = 0; f < 32; ++f)
      BF[f] = *(const f16x8*)(wsh + ((w * 32 + f) * 64 + l) * 8);
    #pragma unroll
    for (int tau = 0; tau < 8; ++tau) {
      int u = (tau >> 1) * 128 + w * 32 + (tau & 1) * 16 + col;   // gate-row index
      biv[tau] = (b_ih1[u] + b_hh1[u]) * LOG2E;
      wxv[tau] = w_ih1[u] * LOG2E;
    }
    #pragma unroll
    for (int c = 0; c < 2; ++c)
      #pragma unroll
      for (int rr = 0; rr < 2; ++rr) {
        int u = w * 32 + c * 16 + col;      // h1 unit
        int r = rb + rr;
        ha[c * 2 + rr] = (u >> 5) * 1024 + (r + ((u >> 3) & 3) * 16) * 16 + (u & 7) * 2;
      }
  } else {
    #pragma unroll
    for (int f = 0; f < 24; ++f)
      BF[f] = *(const f16x8*)(wsh + 65536 + ((w2 * 24 + f) * 64 + l) * 8);
    #pragma unroll
    for (int g = 0; g < 4; ++g) {
      int u = g * 64 + w2 * 16 + col;
      biv[g] = (b_ih2[u] + b_hh2[u]) * LOG2E;
    }
    #pragma unroll
    for (int rr = 0; rr < 2; ++rr) {
      int u2 = w2 * 16 + col;               // h2 unit
      int r = rb + rr;
      ha[rr] = (4 + (u2 >> 5)) * 1024 + (r + ((u2 >> 3) & 3) * 16) * 16 + (u2 & 7) * 2;
    }
  }

  // x -> LDS, zero both h planes
  {
    int r = tid >> 6, cc = (tid & 63) * 8;
    const float4* src = (const float4*)(x + (r0 + r) * 512 + cc);
    float4 v0 = src[0], v1 = src[1];
    *(float4*)(x_lds + r * 516 + cc)     = v0;
    *(float4*)(x_lds + r * 516 + cc + 4) = v1;
  }
  for (int i2 = tid; i2 < 3072; i2 += 512) ((unsigned*)HC)[i2] = 0u;

  float cst[4] = {0.f, 0.f, 0.f, 0.f};
  char* const hcb = (char*)HC;
  __syncthreads();

  #pragma unroll 1
  for (int i = 0; i < TS; i += 2) {
    // interval i (even): PL(i)=plane0, PL(i-1)=plane1
    if (wg == 0)      { L1_BODY(i, hcb, hcb + 6144) }
    else if (i > 0)   { L2_BODY(hcb, hcb + 6144, 1, 0) }
    __syncthreads();
    // interval i+1 (odd): PL(i+1)=plane1, PL(i)=plane0
    if (wg == 0)      { L1_BODY(i + 1, hcb + 6144, hcb) }
    else              { L2_BODY(hcb + 6144, hcb, 1, 0) }
    __syncthreads();
  }
  // interval TS (even): L2 computes h2[TS-1]; no LDS write, store to h2f
  if (wg == 1)        { L2_BODY(hcb, hcb + 6144, 0, 1) }
  __syncthreads();

  // ---- dense head (fp32) ----
  if (tid < 200) {
    int r = tid / 25, d = tid - r * 25;
    float acc = b_d1[d];
    #pragma unroll
    for (int uu = 0; uu < 64; ++uu) acc = fmaf(h2f[r][uu], w_d1[d * 64 + uu], acc);
    dh[tid] = acc;
  }
  __syncthreads();
  if (tid < 8) {
    float y = b_d2[0];
    #pragma unroll
    for (int d = 0; d < 25; ++d) y = fmaf(dh[tid * 25 + d], w_d2[d], y);
    out[r0 + tid] = y;
  }
}

extern "C" void kernel_launch(void* const* d_in, const int* in_sizes, int n_in,
                              void* d_out, int out_size, void* d_ws, size_t ws_size,
                              hipStream_t stream) {
  (void)in_sizes; (void)n_in; (void)out_size; (void)ws_size;
  const float* x     = (const float*)d_in[0];
  const float* w_ih1 = (const float*)d_in[1];
  const float* w_hh1 = (const float*)d_in[2];
  const float* b_ih1 = (const float*)d_in[3];
  const float* b_hh1 = (const float*)d_in[4];
  const float* w_ih2 = (const float*)d_in[5];
  const float* w_hh2 = (const float*)d_in[6];
  const float* b_ih2 = (const float*)d_in[7];
  const float* b_hh2 = (const float*)d_in[8];
  const float* w_d1  = (const float*)d_in[9];
  const float* b_d1  = (const float*)d_in[10];
  const float* w_d2  = (const float*)d_in[11];
  const float* b_d2  = (const float*)d_in[12];
  _Float16* wsh = (_Float16*)d_ws;
  float* outp = (float*)d_out;

  prep<<<224, 512, 0, stream>>>(w_hh1, w_ih2, w_hh2, wsh);
  lstm_mfma<<<256, 512, 0, stream>>>(x, w_ih1, b_ih1, b_hh1, b_ih2, b_hh2,
                                     w_d1, b_d1, w_d2, b_d2, wsh, outp);
}